// Round 2
// baseline (277.801 us; speedup 1.0000x reference)
//
#include <hip/hip_runtime.h>

// VectorQuantizer forward: inputs [64,2048,64] f32, codebook [1024,64] f32.
// Outputs (f32, concat): quantized_ste [8388608], loss [1], indices-as-float [131072].
//
// Round 10: round 9 (scalar-B, 4 rows/thread, MTB=256) proved the scalar path
// works (bank conflicts 5.1M->0.8M, non-FMA VALU gone) but landed latency-
// bound: 80KB LDS -> 2 blocks/CU -> 2 waves/SIMD; s_load(bb) and ds_read(sA)
// share lgkmcnt (unordered across SMEM/LDS -> compiler drains lgkmcnt(0)
// before each FMA block), and 2 waves can't cover the ~200-300cy drains
// (VALUBusy 60%, 40% idle). Fix: MTB=128, 2 rows/thread -> LDS ~39KB ->
// 4 blocks/CU = 4 waves/SIMD. FMA:scalar ratio halves (2 FMAs per bb float)
// but scalar issue is SALU and delivery stays under the scalar-path ceiling;
// the binding constraint (wave-level latency hiding) doubles.
//
// Numerics: identical to rounds 8/9. A-norm = exact 16-dim quarter chains
// (each staging thread computes 2), (p0+p1)+(p2+p3). Dot = single sequential
// fmaf chain k=0..63 per (row,code). d2 = fl(fl(asq - 2*acc) + csq). Argmin:
// strict-less scan in ascending code order per wave (first-index-wins),
// cross-wave merge via u64 (d2bits<<32|idx) min. Loss/STE epilogue in the
// identical 64-row units (2048 identical partials, atomicAdd-accumulated).

#define NROWS  131072
#define DIM    64
#define KCB    1024
#define MTB    128            // rows per block (staged once in LDS)
#define QSIZE  (NROWS * DIM)  // 8388608

__global__ __launch_bounds__(256) void vq_prep(const float* __restrict__ cb,
                                               float* __restrict__ csq,
                                               float* __restrict__ loss_slot) {
    int k = blockIdx.x * 256 + threadIdx.x;
    if (k < KCB) {
        const float* c = cb + k * DIM;
        float a0 = 0.f, a1 = 0.f, a2 = 0.f, a3 = 0.f;
        #pragma unroll
        for (int d = 0; d < 16; ++d) {
            a0 = fmaf(c[d],      c[d],      a0);
            a1 = fmaf(c[16 + d], c[16 + d], a1);
            a2 = fmaf(c[32 + d], c[32 + d], a2);
            a3 = fmaf(c[48 + d], c[48 + d], a3);
        }
        csq[k] = (a0 + a1) + (a2 + a3);
    }
    if (blockIdx.x == 0 && threadIdx.x == 0) *loss_slot = 0.f;  // zero loss accumulator every call
}

__global__ __launch_bounds__(256, 4) void vq_main(const float* __restrict__ x,
                                                  const float* __restrict__ cb,
                                                  const float* __restrict__ csq,
                                                  float* __restrict__ out_q,
                                                  float* __restrict__ out_loss,
                                                  float* __restrict__ out_idx) {
    __shared__ float sA[DIM][MTB];             // 32 KB, dim-major x-tile
    __shared__ float sPart[MTB][4];            // 2 KB, A-norm quarter chains
    __shared__ float sAn[MTB];                 // 0.5 KB, A-norms
    __shared__ unsigned long long sWK[4][MTB]; // 4 KB, per-wave argmin keys
    __shared__ int   sFinal[MTB];              // 0.5 KB
    __shared__ float sLoss[4];
    // total ~39 KB -> 4 blocks/CU = 16 waves/CU = 4 waves/SIMD

    const int tid  = threadIdx.x;
    const int lane = tid & 63;
    const int wid  = tid >> 6;
    const size_t rowbase = (size_t)blockIdx.x * MTB;

    // ---- stage A (128 rows) dim-major + exact A-norm quarter chains ----
    {
        const int r = tid >> 1;      // 0..127
        const int h = tid & 1;       // dim half 32h..32h+31 (= quarters 2h, 2h+1)
        const float4* gx = reinterpret_cast<const float4*>(
            x + (rowbase + (size_t)r) * DIM + 32 * h);
        float4 v0 = gx[0], v1 = gx[1], v2 = gx[2], v3 = gx[3];
        float4 v4 = gx[4], v5 = gx[5], v6 = gx[6], v7 = gx[7];
        float t[32] = {v0.x, v0.y, v0.z, v0.w, v1.x, v1.y, v1.z, v1.w,
                       v2.x, v2.y, v2.z, v2.w, v3.x, v3.y, v3.z, v3.w,
                       v4.x, v4.y, v4.z, v4.w, v5.x, v5.y, v5.z, v5.w,
                       v6.x, v6.y, v6.z, v6.w, v7.x, v7.y, v7.z, v7.w};
        float aq0 = 0.f, aq1 = 0.f;
        #pragma unroll
        for (int j = 0; j < 16; ++j) aq0 = fmaf(t[j],      t[j],      aq0);  // chain 2h
        #pragma unroll
        for (int j = 0; j < 16; ++j) aq1 = fmaf(t[16 + j], t[16 + j], aq1);  // chain 2h+1
        sPart[r][2 * h]     = aq0;
        sPart[r][2 * h + 1] = aq1;
        #pragma unroll
        for (int j = 0; j < 32; ++j) sA[32 * h + j][r] = t[j];   // dim-major scatter
    }
    __syncthreads();
    if (tid < MTB)
        sAn[tid] = (sPart[tid][0] + sPart[tid][1]) + (sPart[tid][2] + sPart[tid][3]);
    __syncthreads();

    // ---- per-thread rows: r0, r0+1; per-wave codes: quarter [wu*256, wu*256+256) ----
    const int r0 = 2 * lane;
    float asq[2];
    {
        const float2 a = *reinterpret_cast<const float2*>(&sAn[r0]);
        asq[0] = a.x; asq[1] = a.y;
    }
    const int wu = __builtin_amdgcn_readfirstlane(wid);   // provably uniform wave id
    const float* cbw = cb  + (size_t)wu * 256 * DIM;      // uniform -> scalar loads
    const float* csw = csq + wu * 256;                    // uniform -> scalar loads

    float kd[2] = {__builtin_inff(), __builtin_inff()};
    int   ki[2] = {0, 0};

    #pragma unroll 1
    for (int g = 0; g < 32; ++g) {           // 8 codes per group, uniform
        const float* bp = cbw + (size_t)g * 8 * DIM;
        float acc[2][8];
        #pragma unroll
        for (int r = 0; r < 2; ++r)
            #pragma unroll
            for (int c = 0; c < 8; ++c) acc[r][c] = 0.f;

        #pragma unroll 1
        for (int kc = 0; kc < 8; ++kc) {     // 8 dims per chunk
            const float* bkc = bp + 8 * kc;
            float bb[8][8];                  // uniform values -> SGPRs
            #pragma unroll
            for (int c = 0; c < 8; ++c) {
                const float4 u0 = *reinterpret_cast<const float4*>(bkc + 64 * c);
                const float4 u1 = *reinterpret_cast<const float4*>(bkc + 64 * c + 4);
                bb[c][0] = u0.x; bb[c][1] = u0.y; bb[c][2] = u0.z; bb[c][3] = u0.w;
                bb[c][4] = u1.x; bb[c][5] = u1.y; bb[c][6] = u1.z; bb[c][7] = u1.w;
            }
            #pragma unroll
            for (int k8 = 0; k8 < 8; ++k8) {
                const int k = 8 * kc + k8;   // sequential k-chain 0..63 preserved
                const float2 av = *reinterpret_cast<const float2*>(&sA[k][r0]);
                const float a0 = av.x, a1 = av.y;
                #pragma unroll
                for (int c = 0; c < 8; ++c) {
                    const float bf = bb[c][k8];          // SGPR operand
                    acc[0][c] = fmaf(a0, bf, acc[0][c]);
                    acc[1][c] = fmaf(a1, bf, acc[1][c]);
                }
            }
        }

        // ---- tail: d2 + argmin update (ref expression roundings preserved) ----
        const float4 cs0 = *reinterpret_cast<const float4*>(csw + 8 * g);
        const float4 cs1 = *reinterpret_cast<const float4*>(csw + 8 * g + 4);
        const float css[8] = {cs0.x, cs0.y, cs0.z, cs0.w, cs1.x, cs1.y, cs1.z, cs1.w};
        const int nb = (wu << 8) + (g << 3);
        #pragma unroll
        for (int c = 0; c < 8; ++c) {
            const float cs = css[c];
            const int n = nb + c;
            #pragma unroll
            for (int r = 0; r < 2; ++r) {
                const float tt = asq[r] - 2.0f * acc[r][c];  // one rounding (2*acc exact)
                const float dd = tt + cs;                    // second rounding
                const bool lt = dd < kd[r];                  // strict-less: first-index-wins
                kd[r] = lt ? dd : kd[r];
                ki[r] = lt ? n  : ki[r];
            }
        }
    }

    // ---- cross-wave argmin merge (u64 keys, order-free, first-index-wins) ----
    #pragma unroll
    for (int i = 0; i < 2; ++i)
        sWK[wid][r0 + i] =
            ((unsigned long long)__float_as_uint(kd[i]) << 32) | (unsigned)ki[i];
    __syncthreads();
    if (tid < MTB) {
        unsigned long long b0 = sWK[0][tid], b1 = sWK[1][tid];
        unsigned long long b2 = sWK[2][tid], b3 = sWK[3][tid];
        unsigned long long m01 = b0 < b1 ? b0 : b1;
        unsigned long long m23 = b2 < b3 ? b2 : b3;
        unsigned long long fk  = m01 < m23 ? m01 : m23;
        const int idx = (int)(unsigned)fk;
        sFinal[tid] = idx;
        out_idx[rowbase + tid] = (float)idx;
    }
    __syncthreads();

    // ---- epilogue: coalesced STE write + loss, in round-8-identical 64-row units ----
    #pragma unroll 1
    for (int sub = 0; sub < 2; ++sub) {
        const size_t base = (rowbase + 64 * sub) * DIM;
        float lsum = 0.f;
        #pragma unroll 4
        for (int i = tid; i < 64 * DIM; i += 256) {
            const int r = i >> 6;
            const int d = i & 63;
            const int kb = sFinal[64 * sub + r];   // wave-uniform per iteration
            const float q  = cb[(size_t)kb * DIM + d];
            const float xe = x[base + i];
            out_q[base + i] = xe + (q - xe);        // STE forward, ref's rounding
            const float df = q - xe;
            lsum = fmaf(df, df, lsum);
        }
        #pragma unroll
        for (int off = 32; off; off >>= 1) lsum += __shfl_down(lsum, off, 64);
        if (lane == 0) sLoss[wid] = lsum;
        __syncthreads();
        if (tid == 0) {
            const float tot = (sLoss[0] + sLoss[1]) + (sLoss[2] + sLoss[3]);
            atomicAdd(out_loss, tot * (1.25f / 8388608.0f));  // (q + 0.25*e) / count
        }
        __syncthreads();
    }
}

extern "C" void kernel_launch(void* const* d_in, const int* in_sizes, int n_in,
                              void* d_out, int out_size, void* d_ws, size_t ws_size,
                              hipStream_t stream) {
    const float* x  = (const float*)d_in[0];   // 8388608
    const float* cb = (const float*)d_in[1];   // 65536
    float* out      = (float*)d_out;
    float* out_loss = out + QSIZE;             // [8388608]
    float* out_idx  = out + QSIZE + 1;         // [8388609 .. 8519680]
    float* csq      = (float*)d_ws;            // 1024 floats scratch

    vq_prep<<<4, 256, 0, stream>>>(cb, csq, out_loss);
    vq_main<<<NROWS / MTB, 256, 0, stream>>>(x, cb, csq, out, out_loss, out_idx);
}

// Round 4
// 265.633 us; speedup vs baseline: 1.0458x; 1.0458x over previous
//
#include <hip/hip_runtime.h>

// VectorQuantizer forward: inputs [64,2048,64] f32, codebook [1024,64] f32.
// Outputs (f32, concat): quantized_ste [8388608], loss [1], indices-as-float [131072].
//
// Round 12 = round 11 resubmitted verbatim (bench infra died twice; no kernel
// verdict). Theory: rounds 9 (W=2 waves/SIMD, C=512 cyc/chunk) and 10 (W=4,
// C=256) landed equal (236/228us, VALUBusy 60/66%) -> the stall is the
// per-chunk lgkmcnt(0) drain for bb s_loads (SMEM returns out-of-order =>
// full drain is the only legal wait => SGPR prefetch impossible), L ~ 1100
// cyc, and latency coverage W*C was invariant at 1024 because rows/thread =
// MTB/64 (wave-uniform codes) while LDS ~ MTB caps blocks/CU. Break it with
// a 512-THREAD block: MTB=256 -> 4 rows/thread (C=512 cyc), 8 waves each
// owning a uniform 128-code slice, 2 blocks/CU (=4 waves/SIMD, W=4):
// coverage 2048 ~ 2L. SMEM traffic also halves vs round 10 (bb float feeds
// 4 FMAs). Post-GEMM sWK/sFinal/sLoss alias into the dead sA buffer to keep
// LDS at ~70.7KB (round 9's 80KB proves >64KB static works).
//
// Numerics: identical to rounds 8-10. A-norm = exact 16-dim quarter chains,
// (p0+p1)+(p2+p3). Dot = single sequential fmaf chain k=0..63 per (row,code).
// d2 = fl(fl(asq - 2*acc) + csq). Argmin: strict-less scan in ascending code
// order per wave (8 disjoint ascending 128-code slices), cross-wave merge via
// u64 (d2bits<<32|idx) min (order-free, first-index-wins). Loss/STE epilogue
// = round 9 verbatim (tid<256, 4x 64-row units -> identical 2048 partials).

#define NROWS  131072
#define DIM    64
#define KCB    1024
#define MTB    256            // rows per block (staged once in LDS)
#define QSIZE  (NROWS * DIM)  // 8388608

typedef unsigned long long u64;

__global__ __launch_bounds__(256) void vq_prep(const float* __restrict__ cb,
                                               float* __restrict__ csq,
                                               float* __restrict__ loss_slot) {
    int k = blockIdx.x * 256 + threadIdx.x;
    if (k < KCB) {
        const float* c = cb + k * DIM;
        float a0 = 0.f, a1 = 0.f, a2 = 0.f, a3 = 0.f;
        #pragma unroll
        for (int d = 0; d < 16; ++d) {
            a0 = fmaf(c[d],      c[d],      a0);
            a1 = fmaf(c[16 + d], c[16 + d], a1);
            a2 = fmaf(c[32 + d], c[32 + d], a2);
            a3 = fmaf(c[48 + d], c[48 + d], a3);
        }
        csq[k] = (a0 + a1) + (a2 + a3);
    }
    if (blockIdx.x == 0 && threadIdx.x == 0) *loss_slot = 0.f;  // zero loss accumulator every call
}

__global__ __launch_bounds__(512, 4) void vq_main(const float* __restrict__ x,
                                                  const float* __restrict__ cb,
                                                  const float* __restrict__ csq,
                                                  float* __restrict__ out_q,
                                                  float* __restrict__ out_loss,
                                                  float* __restrict__ out_idx) {
    // 64 KB region: sA during GEMM; sWK/sFinal/sLoss after (all post-GEMM,
    // fenced by __syncthreads before first aliased write).
    __shared__ __align__(16) char smem[DIM * MTB * 4];
    float (*sA)[MTB] = reinterpret_cast<float (*)[MTB]>(smem);             // [64][256] f32
    u64   (*sWK)[MTB] = reinterpret_cast<u64 (*)[MTB]>(smem);              // [8][256] u64 = 16 KB
    int*   sFinal = reinterpret_cast<int*>(smem + 8 * MTB * 8);            // +16 KB, [256]
    float* sLoss  = reinterpret_cast<float*>(smem + 8 * MTB * 8 + MTB * 4);// +17 KB, [4]
    __shared__ __align__(16) float sPart[MTB][4];  // 4 KB, A-norm quarter chains (staging-live)
    __shared__ __align__(16) float sAn[MTB];       // 1 KB, A-norms (GEMM-live)
    // total ~70.7 KB -> 2 blocks/CU = 16 waves/CU = 4 waves/SIMD

    const int tid  = threadIdx.x;
    const int lane = tid & 63;
    const int wid  = tid >> 6;           // 0..7
    const size_t rowbase = (size_t)blockIdx.x * MTB;

    // ---- stage A (256 rows) dim-major + exact A-norm quarter chains ----
    {
        const int r = tid >> 1;      // 0..255
        const int h = tid & 1;       // dim half 32h..32h+31 (= quarters 2h, 2h+1)
        const float4* gx = reinterpret_cast<const float4*>(
            x + (rowbase + (size_t)r) * DIM + 32 * h);
        float4 v0 = gx[0], v1 = gx[1], v2 = gx[2], v3 = gx[3];
        float4 v4 = gx[4], v5 = gx[5], v6 = gx[6], v7 = gx[7];
        float t[32] = {v0.x, v0.y, v0.z, v0.w, v1.x, v1.y, v1.z, v1.w,
                       v2.x, v2.y, v2.z, v2.w, v3.x, v3.y, v3.z, v3.w,
                       v4.x, v4.y, v4.z, v4.w, v5.x, v5.y, v5.z, v5.w,
                       v6.x, v6.y, v6.z, v6.w, v7.x, v7.y, v7.z, v7.w};
        float aq0 = 0.f, aq1 = 0.f;
        #pragma unroll
        for (int j = 0; j < 16; ++j) aq0 = fmaf(t[j],      t[j],      aq0);  // chain 2h
        #pragma unroll
        for (int j = 0; j < 16; ++j) aq1 = fmaf(t[16 + j], t[16 + j], aq1);  // chain 2h+1
        sPart[r][2 * h]     = aq0;
        sPart[r][2 * h + 1] = aq1;
        #pragma unroll
        for (int j = 0; j < 32; ++j) sA[32 * h + j][r] = t[j];   // dim-major scatter
    }
    __syncthreads();
    if (tid < MTB)
        sAn[tid] = (sPart[tid][0] + sPart[tid][1]) + (sPart[tid][2] + sPart[tid][3]);
    __syncthreads();

    // ---- per-thread rows: r0..r0+3; per-wave codes: slice [wid*128, wid*128+128) ----
    const int r0 = 4 * lane;
    float asq[4];
    {
        const float4 an = *reinterpret_cast<const float4*>(&sAn[r0]);
        asq[0] = an.x; asq[1] = an.y; asq[2] = an.z; asq[3] = an.w;
    }
    const int cu = __builtin_amdgcn_readfirstlane(wid);   // provably uniform wave id 0..7
    const float* cbw = cb  + (size_t)cu * 128 * DIM;      // uniform -> scalar loads
    const float* csw = csq + cu * 128;                    // uniform -> scalar loads

    float kd[4] = {__builtin_inff(), __builtin_inff(), __builtin_inff(), __builtin_inff()};
    int   ki[4] = {0, 0, 0, 0};

    #pragma unroll 1
    for (int g = 0; g < 16; ++g) {           // 8 codes per group, uniform
        const float* bp = cbw + (size_t)g * 8 * DIM;
        float acc[4][8];
        #pragma unroll
        for (int r = 0; r < 4; ++r)
            #pragma unroll
            for (int c = 0; c < 8; ++c) acc[r][c] = 0.f;

        #pragma unroll 1
        for (int kc = 0; kc < 8; ++kc) {     // 8 dims per chunk (64 SGPR bb)
            const float* bkc = bp + 8 * kc;
            float bb[8][8];                  // uniform values -> SGPRs
            #pragma unroll
            for (int c = 0; c < 8; ++c) {
                const float4 u0 = *reinterpret_cast<const float4*>(bkc + 64 * c);
                const float4 u1 = *reinterpret_cast<const float4*>(bkc + 64 * c + 4);
                bb[c][0] = u0.x; bb[c][1] = u0.y; bb[c][2] = u0.z; bb[c][3] = u0.w;
                bb[c][4] = u1.x; bb[c][5] = u1.y; bb[c][6] = u1.z; bb[c][7] = u1.w;
            }
            #pragma unroll
            for (int k8 = 0; k8 < 8; ++k8) { // sequential k-chain 0..63 preserved
                const float4 av = *reinterpret_cast<const float4*>(&sA[8 * kc + k8][r0]);
                #pragma unroll
                for (int c = 0; c < 8; ++c) {
                    const float bf = bb[c][k8];          // SGPR operand
                    acc[0][c] = fmaf(av.x, bf, acc[0][c]);
                    acc[1][c] = fmaf(av.y, bf, acc[1][c]);
                    acc[2][c] = fmaf(av.z, bf, acc[2][c]);
                    acc[3][c] = fmaf(av.w, bf, acc[3][c]);
                }
            }
        }

        // ---- tail: d2 + argmin update (ref expression roundings preserved) ----
        const float4 cs0 = *reinterpret_cast<const float4*>(csw + 8 * g);
        const float4 cs1 = *reinterpret_cast<const float4*>(csw + 8 * g + 4);
        const float css[8] = {cs0.x, cs0.y, cs0.z, cs0.w, cs1.x, cs1.y, cs1.z, cs1.w};
        const int nb = (cu << 7) + (g << 3);
        #pragma unroll
        for (int c = 0; c < 8; ++c) {
            const float cs = css[c];
            const int n = nb + c;
            #pragma unroll
            for (int r = 0; r < 4; ++r) {
                const float tt = asq[r] - 2.0f * acc[r][c];  // one rounding (2*acc exact)
                const float dd = tt + cs;                    // second rounding
                const bool lt = dd < kd[r];                  // strict-less: first-index-wins
                kd[r] = lt ? dd : kd[r];
                ki[r] = lt ? n  : ki[r];
            }
        }
    }

    // ---- cross-wave argmin merge (u64 keys, order-free, first-index-wins) ----
    __syncthreads();                         // all sA reads done -> safe to alias sWK
    #pragma unroll
    for (int i = 0; i < 4; ++i)
        sWK[wid][r0 + i] =
            ((u64)__float_as_uint(kd[i]) << 32) | (unsigned)ki[i];
    __syncthreads();
    if (tid < MTB) {
        u64 m = sWK[0][tid];
        #pragma unroll
        for (int w = 1; w < 8; ++w) {
            const u64 b = sWK[w][tid];
            m = b < m ? b : m;               // u64 min: associative/commutative
        }
        const int idx = (int)(unsigned)m;
        sFinal[tid] = idx;
        out_idx[rowbase + tid] = (float)idx;
    }
    __syncthreads();

    // ---- epilogue: round-9 verbatim (tid<256, 4x 64-row units, identical partials) ----
    #pragma unroll 1
    for (int sub = 0; sub < 4; ++sub) {
        if (tid < 256) {
            const size_t base = (rowbase + 64 * sub) * DIM;
            float lsum = 0.f;
            #pragma unroll 4
            for (int i = tid; i < 64 * DIM; i += 256) {
                const int r = i >> 6;
                const int d = i & 63;
                const int kb = sFinal[64 * sub + r];   // wave-uniform per iteration
                const float q  = cb[(size_t)kb * DIM + d];
                const float xe = x[base + i];
                out_q[base + i] = xe + (q - xe);        // STE forward, ref's rounding
                const float df = q - xe;
                lsum = fmaf(df, df, lsum);
            }
            #pragma unroll
            for (int off = 32; off; off >>= 1) lsum += __shfl_down(lsum, off, 64);
            if (lane == 0) sLoss[wid] = lsum;
        }
        __syncthreads();
        if (tid == 0) {
            const float tot = (sLoss[0] + sLoss[1]) + (sLoss[2] + sLoss[3]);
            atomicAdd(out_loss, tot * (1.25f / 8388608.0f));  // (q + 0.25*e) / count
        }
        __syncthreads();
    }
}

extern "C" void kernel_launch(void* const* d_in, const int* in_sizes, int n_in,
                              void* d_out, int out_size, void* d_ws, size_t ws_size,
                              hipStream_t stream) {
    const float* x  = (const float*)d_in[0];   // 8388608
    const float* cb = (const float*)d_in[1];   // 65536
    float* out      = (float*)d_out;
    float* out_loss = out + QSIZE;             // [8388608]
    float* out_idx  = out + QSIZE + 1;         // [8388609 .. 8519680]
    float* csq      = (float*)d_ws;            // 1024 floats scratch

    vq_prep<<<4, 256, 0, stream>>>(cb, csq, out_loss);
    vq_main<<<NROWS / MTB, 512, 0, stream>>>(x, cb, csq, out, out_loss, out_idx);
}